// Round 1
// baseline (218.841 us; speedup 1.0000x reference)
//
#include <hip/hip_runtime.h>

#define VV   50257
#define EE   512
#define HH   1024
#define TT   512
#define SS   8
#define TSS  128
#define MOOV 20

// ws layout (floats)
#define OFF_Q      0        // 1024
#define OFF_COMB   1024     // 3584 : [emb(512) | c_enc(1024) | c_name(1024) | c_type(1024)]
#define OFF_SENC   4608     // 512
#define OFF_SNAME  5120     // 1024
#define OFF_STYPE  6144     // 1024
#define OFF_X      7168     // 512
#define OFF_GATES  7680     // 4096
#define OFF_H1     11776    // 1024
#define OFF_C1     12800    // 1024
#define OFF_GENP   13824    // 1
#define OFF_SUMEXP 13825    // 1
#define OFF_SIM    13832    // 8
#define OFF_QC     13840    // 1024
#define OFF_ATTN   14864    // 1024
#define OFF_LOGIT  15888    // 50257 (stores exp(logit))

__device__ __forceinline__ float dot4(float4 a, float4 b) {
    return a.x*b.x + a.y*b.y + a.z*b.z + a.w*b.w;
}
__device__ __forceinline__ float wred(float v) {
    #pragma unroll
    for (int o = 32; o; o >>= 1) v += __shfl_down(v, o, 64);
    return v;
}
__device__ __forceinline__ float wred_all(float v) {
    #pragma unroll
    for (int o = 32; o; o >>= 1) v += __shfl_xor(v, o, 64);
    return v;
}
__device__ __forceinline__ float wmax_all(float v) {
    #pragma unroll
    for (int o = 32; o; o >>= 1) v = fmaxf(v, __shfl_xor(v, o, 64));
    return v;
}

// K1: zero scratch regions, copy emb into comb, compute q = W_ma_attn @ emb + b
__global__ void k_init_q(const float* __restrict__ emb, const float* __restrict__ W,
                         const float* __restrict__ bias, float* __restrict__ ws) {
    int tid = threadIdx.x, bid = blockIdx.x;
    int gid = bid * 256 + tid;
    if (gid < 3072) ws[OFF_COMB + 512 + gid] = 0.f;   // c_enc/c_name/c_type accumulators
    if (gid == 3072) ws[OFF_SUMEXP] = 0.f;
    if (gid < 512) ws[OFF_COMB + gid] = emb[gid];
    int wave = tid >> 6, lane = tid & 63;
    int row = bid * 4 + wave;                          // < 1024
    const float4* Wr = (const float4*)(W + (size_t)row * EE);
    const float4* e4 = (const float4*)emb;
    float s = dot4(Wr[lane], e4[lane]) + dot4(Wr[lane + 64], e4[lane + 64]);
    s = wred(s);
    if (lane == 0) ws[OFF_Q + row] = s + bias[row];
}

// K2: attention scores (enc 512, name 1024, type 1024 rows) + sim (block 640)
__global__ void k_scores(const float* __restrict__ enc, const float* __restrict__ name,
                         const float* __restrict__ type, float* __restrict__ ws) {
    int b = blockIdx.x, tid = threadIdx.x;
    int wave = tid >> 6, lane = tid & 63;
    if (b < 640) {
        const float* src; float* dst; int r;
        if (b < 128)      { src = enc;  dst = ws + OFF_SENC;  r = b * 4 + wave; }
        else if (b < 384) { src = name; dst = ws + OFF_SNAME; r = (b - 128) * 4 + wave; }
        else              { src = type; dst = ws + OFF_STYPE; r = (b - 384) * 4 + wave; }
        const float4* R  = (const float4*)(src + (size_t)r * HH);
        const float4* q4 = (const float4*)(ws + OFF_Q);
        float s = 0.f;
        #pragma unroll
        for (int k = 0; k < 4; ++k) s += dot4(R[lane + 64 * k], q4[lane + 64 * k]);
        s = wred(s);
        if (lane == 0) dst[r] = s;
    } else {
        // sim = softmax(enc_last @ name_hiddens[:, -1, :].T)
        __shared__ float sd[8];
        const float4* el = (const float4*)(enc + (size_t)(TT - 1) * HH);
        for (int s8 = wave; s8 < 8; s8 += 4) {
            const float4* R = (const float4*)(name + ((size_t)s8 * TSS + (TSS - 1)) * HH);
            float s = 0.f;
            #pragma unroll
            for (int k = 0; k < 4; ++k) s += dot4(R[lane + 64 * k], el[lane + 64 * k]);
            s = wred(s);
            if (lane == 0) sd[s8] = s;
        }
        __syncthreads();
        if (tid == 0) {
            float m = -1e30f;
            for (int i = 0; i < 8; ++i) m = fmaxf(m, sd[i]);
            float e[8], su = 0.f;
            for (int i = 0; i < 8; ++i) { e[i] = expf(sd[i] - m); su += e[i]; }
            for (int i = 0; i < 8; ++i) ws[OFF_SIM + i] = e[i] / su;
        }
    }
}

// K3: softmax each score segment in place (3 blocks x 1024 threads)
__global__ void k_softmax3(float* __restrict__ ws) {
    __shared__ float red[16];
    __shared__ float bval;
    int b = blockIdx.x, tid = threadIdx.x;
    int n = (b == 0) ? 512 : 1024;
    float* s = ws + ((b == 0) ? OFF_SENC : (b == 1) ? OFF_SNAME : OFF_STYPE);
    float v = (tid < n) ? s[tid] : -1e30f;
    float m = v;
    #pragma unroll
    for (int o = 32; o; o >>= 1) m = fmaxf(m, __shfl_xor(m, o, 64));
    if ((tid & 63) == 0) red[tid >> 6] = m;
    __syncthreads();
    if (tid == 0) { float mm = red[0]; for (int i = 1; i < 16; ++i) mm = fmaxf(mm, red[i]); bval = mm; }
    __syncthreads();
    m = bval;
    float e  = (tid < n) ? expf(v - m) : 0.f;
    float su = e;
    #pragma unroll
    for (int o = 32; o; o >>= 1) su += __shfl_xor(su, o, 64);
    __syncthreads();
    if ((tid & 63) == 0) red[tid >> 6] = su;
    __syncthreads();
    if (tid == 0) { float ss = 0.f; for (int i = 0; i < 16; ++i) ss += red[i]; bval = ss; }
    __syncthreads();
    if (tid < n) s[tid] = e / bval;
}

// K4: context vectors c_* += sum_r s[r]*arg[r, col]  (atomic accumulate into comb)
__global__ void k_ctx(const float* __restrict__ enc, const float* __restrict__ name,
                      const float* __restrict__ type, float* __restrict__ ws) {
    int b = blockIdx.x, tid = threadIdx.x;
    const float* src; const float* sw; float* dst; int i;
    if (b < 64)       { i = b;       src = enc;  sw = ws + OFF_SENC;  dst = ws + OFF_COMB + 512;  }
    else if (b < 192) { i = b - 64;  src = name; sw = ws + OFF_SNAME; dst = ws + OFF_COMB + 1536; }
    else              { i = b - 192; src = type; sw = ws + OFF_STYPE; dst = ws + OFF_COMB + 2560; }
    int cc = i & 3;
    int r0 = (i >> 2) * 32;
    int col = cc * 256 + tid;
    float acc = 0.f;
    #pragma unroll 4
    for (int r = r0; r < r0 + 32; ++r) acc += sw[r] * src[(size_t)r * HH + col];
    atomicAdd(&dst[col], acc);
}

// K5: x = tanh(W_ma_comb @ comb + b)   (512 rows x 3584)
__global__ void k_x(const float* __restrict__ W, const float* __restrict__ bias,
                    float* __restrict__ ws) {
    int tid = threadIdx.x, wave = tid >> 6, lane = tid & 63;
    int row = blockIdx.x * 4 + wave;                   // < 512
    const float4* Wr = (const float4*)(W + (size_t)row * 3584);
    const float4* c4 = (const float4*)(ws + OFF_COMB);
    float s = 0.f;
    #pragma unroll
    for (int k = 0; k < 14; ++k) s += dot4(Wr[lane + 64 * k], c4[lane + 64 * k]);
    s = wred(s);
    if (lane == 0) ws[OFF_X + row] = tanhf(s + bias[row]);
}

// K6: gates = W_ih @ x + W_hh @ h0 + b_ih + b_hh   (4096 rows)
__global__ void k_gates(const float* __restrict__ Wih, const float* __restrict__ Whh,
                        const float* __restrict__ bih, const float* __restrict__ bhh,
                        const float* __restrict__ h0, float* __restrict__ ws) {
    int tid = threadIdx.x, wave = tid >> 6, lane = tid & 63;
    int row = blockIdx.x * 4 + wave;                   // < 4096
    const float4* Wi = (const float4*)(Wih + (size_t)row * EE);
    const float4* x4 = (const float4*)(ws + OFF_X);
    float s = dot4(Wi[lane], x4[lane]) + dot4(Wi[lane + 64], x4[lane + 64]);
    const float4* Wh = (const float4*)(Whh + (size_t)row * HH);
    const float4* h4 = (const float4*)h0;
    #pragma unroll
    for (int k = 0; k < 4; ++k) s += dot4(Wh[lane + 64 * k], h4[lane + 64 * k]);
    s = wred(s);
    if (lane == 0) ws[OFF_GATES + row] = s + bih[row] + bhh[row];
}

// K7: LSTM cell -> h1,c1 (to ws and d_out); then gen_p
__global__ void k_lstm(const float* __restrict__ c0, const float* __restrict__ nameh,
                       const float* __restrict__ typeh, const float* __restrict__ Wg,
                       const float* __restrict__ bg, float* __restrict__ ws,
                       float* __restrict__ out) {
    int t = threadIdx.x;                               // 1024 threads
    float ig = ws[OFF_GATES + t], fg = ws[OFF_GATES + 1024 + t];
    float gg = ws[OFF_GATES + 2048 + t], og = ws[OFF_GATES + 3072 + t];
    ig = 1.f / (1.f + expf(-ig));
    fg = 1.f / (1.f + expf(-fg));
    og = 1.f / (1.f + expf(-og));
    float c1 = fg * c0[t] + ig * tanhf(gg);
    float h1 = og * tanhf(c1);
    ws[OFF_C1 + t] = c1; ws[OFF_H1 + t] = h1;
    out[VV + MOOV + t] = h1;
    out[VV + MOOV + 1024 + t] = c1;
    __syncthreads();
    // gen_p = sigmoid(W_gen @ [h1, name_h, type_h, x] + b_gen)
    float p = Wg[t] * h1 + Wg[1024 + t] * nameh[t] + Wg[2048 + t] * typeh[t];
    if (t < 512) p += Wg[3072 + t] * ws[OFF_X + t];
    __shared__ float red[16];
    float su = p;
    #pragma unroll
    for (int o = 32; o; o >>= 1) su += __shfl_xor(su, o, 64);
    if ((t & 63) == 0) red[t >> 6] = su;
    __syncthreads();
    if (t == 0) {
        float ss = 0.f;
        for (int i = 0; i < 16; ++i) ss += red[i];
        ws[OFF_GENP] = 1.f / (1.f + expf(-(ss + bg[0])));
    }
}

// K8: qc = W_copy @ h1 + b_copy
__global__ void k_qc(const float* __restrict__ W, const float* __restrict__ bias,
                     float* __restrict__ ws) {
    int tid = threadIdx.x, wave = tid >> 6, lane = tid & 63;
    int row = blockIdx.x * 4 + wave;                   // < 1024
    const float4* Wr = (const float4*)(W + (size_t)row * HH);
    const float4* h4 = (const float4*)(ws + OFF_H1);
    float s = 0.f;
    #pragma unroll
    for (int k = 0; k < 4; ++k) s += dot4(Wr[lane + 64 * k], h4[lane + 64 * k]);
    s = wred(s);
    if (lane == 0) ws[OFF_QC + row] = s + bias[row];
}

// K9: attn scores[s,t] = type_hiddens[s,t,:] . qc
__global__ void k_attn(const float* __restrict__ type, float* __restrict__ ws) {
    int tid = threadIdx.x, wave = tid >> 6, lane = tid & 63;
    int row = blockIdx.x * 4 + wave;                   // < 1024
    const float4* R  = (const float4*)(type + (size_t)row * HH);
    const float4* q4 = (const float4*)(ws + OFF_QC);
    float s = 0.f;
    #pragma unroll
    for (int k = 0; k < 4; ++k) s += dot4(R[lane + 64 * k], q4[lane + 64 * k]);
    s = wred(s);
    if (lane == 0) ws[OFF_ATTN + row] = s;
}

// K10: big matvec exp(W_out @ h1 + b_out), accumulate sumexp via per-block atomics
__global__ void k_big(const float* __restrict__ W, const float* __restrict__ bias,
                      float* __restrict__ ws) {
    int tid = threadIdx.x, wave = tid >> 6, lane = tid & 63;
    int row = blockIdx.x * 4 + wave;
    __shared__ float part[4];
    float e = 0.f;
    if (row < VV) {
        const float4* Wr = (const float4*)(W + (size_t)row * HH);
        const float4* h4 = (const float4*)(ws + OFF_H1);
        float s = 0.f;
        #pragma unroll
        for (int k = 0; k < 4; ++k) s += dot4(Wr[lane + 64 * k], h4[lane + 64 * k]);
        s = wred(s);
        if (lane == 0) { e = expf(s + bias[row]); ws[OFF_LOGIT + row] = e; }
    }
    if (lane == 0) part[wave] = e;
    __syncthreads();
    if (tid == 0) atomicAdd(&ws[OFF_SUMEXP], part[0] + part[1] + part[2] + part[3]);
}

// K11: out[v] = gen_p * p_vocab[v]
__global__ void k_final1(const float* __restrict__ ws, float* __restrict__ out) {
    int g = blockIdx.x * 256 + threadIdx.x;
    if (g >= VV + MOOV) return;
    float gp = ws[OFF_GENP];
    float pv = (g < VV) ? ws[OFF_LOGIT + g] / ws[OFF_SUMEXP] : 0.f;
    out[g] = gp * pv;
}

// K12: per-s softmax over attn scores, scatter (1-gen_p)*sim[s]*attn_p into out
__global__ void k_scatter(const int* __restrict__ idx, const float* __restrict__ ws,
                          float* __restrict__ out) {
    int tid = threadIdx.x, s = tid >> 6, lane = tid & 63;   // 512 threads = 8 waves
    float sc0 = ws[OFF_ATTN + s * TSS + lane];
    float sc1 = ws[OFF_ATTN + s * TSS + 64 + lane];
    float m = wmax_all(fmaxf(sc0, sc1));
    float e0 = expf(sc0 - m), e1 = expf(sc1 - m);
    float su = wred_all(e0 + e1);
    float scale = (1.f - ws[OFF_GENP]) * ws[OFF_SIM + s] / su;
    atomicAdd(&out[idx[s * TSS + lane]],      scale * e0);
    atomicAdd(&out[idx[s * TSS + 64 + lane]], scale * e1);
}

// K13: log(clip(prob))
__global__ void k_final2(float* __restrict__ out) {
    int g = blockIdx.x * 256 + threadIdx.x;
    if (g >= VV + MOOV) return;
    out[g] = logf(fmaxf(out[g], 1e-10f));
}

extern "C" void kernel_launch(void* const* d_in, const int* in_sizes, int n_in,
                              void* d_out, int out_size, void* d_ws, size_t ws_size,
                              hipStream_t stream) {
    (void)in_sizes; (void)n_in; (void)out_size; (void)ws_size;
    const float* emb   = (const float*)d_in[0];
    const float* h0    = (const float*)d_in[1];
    const float* c0    = (const float*)d_in[2];
    const float* enc   = (const float*)d_in[3];
    const float* name  = (const float*)d_in[4];
    const float* type  = (const float*)d_in[5];
    const float* nameh = (const float*)d_in[6];
    const float* typeh = (const float*)d_in[7];
    const float* Wma   = (const float*)d_in[8];
    const float* bma   = (const float*)d_in[9];
    const float* Wmc   = (const float*)d_in[10];
    const float* bmc   = (const float*)d_in[11];
    const float* Wih   = (const float*)d_in[12];
    const float* Whh   = (const float*)d_in[13];
    const float* bih   = (const float*)d_in[14];
    const float* bhh   = (const float*)d_in[15];
    const float* Wcp   = (const float*)d_in[16];
    const float* bcp   = (const float*)d_in[17];
    const float* Wg    = (const float*)d_in[18];
    const float* bg    = (const float*)d_in[19];
    const float* Wout  = (const float*)d_in[20];
    const float* bout  = (const float*)d_in[21];
    const int*   tidx  = (const int*)d_in[22];
    float* out = (float*)d_out;
    float* ws  = (float*)d_ws;

    k_init_q  <<<256,   256, 0, stream>>>(emb, Wma, bma, ws);
    k_scores  <<<641,   256, 0, stream>>>(enc, name, type, ws);
    k_softmax3<<<3,    1024, 0, stream>>>(ws);
    k_ctx     <<<320,   256, 0, stream>>>(enc, name, type, ws);
    k_x       <<<128,   256, 0, stream>>>(Wmc, bmc, ws);
    k_gates   <<<1024,  256, 0, stream>>>(Wih, Whh, bih, bhh, h0, ws);
    k_lstm    <<<1,    1024, 0, stream>>>(c0, nameh, typeh, Wg, bg, ws, out);
    k_qc      <<<256,   256, 0, stream>>>(Wcp, bcp, ws);
    k_attn    <<<256,   256, 0, stream>>>(type, ws);
    k_big     <<<12565, 256, 0, stream>>>(Wout, bout, ws);
    k_final1  <<<197,   256, 0, stream>>>(ws, out);
    k_scatter <<<1,     512, 0, stream>>>(tidx, ws, out);
    k_final2  <<<197,   256, 0, stream>>>(out);
}

// Round 2
// 108.328 us; speedup vs baseline: 2.0202x; 2.0202x over previous
//
#include <hip/hip_runtime.h>

#define VV   50257
#define EE   512
#define HH   1024
#define TT   512
#define SS   8
#define TSS  128
#define MOOV 20

// ws layout (floats)
#define OFF_Q      0        // 1024
#define OFF_COMB   1024     // 3584 : [emb(512) | c_enc(1024) | c_name(1024) | c_type(1024)]
#define OFF_SENC   4608     // 512
#define OFF_SNAME  5120     // 1024
#define OFF_STYPE  6144     // 1024
#define OFF_X      7168     // 512
#define OFF_GATES  7680     // 4096
#define OFF_H1     11776    // 1024
#define OFF_C1     12800    // 1024
#define OFF_GENP   13824    // 1
#define OFF_SUMEXP 13825    // 1
#define OFF_SIM    13832    // 8
#define OFF_QC     13840    // 1024
#define OFF_ATTN   14864    // 1024
#define OFF_LOGIT  15888    // 50257 (stores exp(logit))

__device__ __forceinline__ float dot4(float4 a, float4 b) {
    return a.x*b.x + a.y*b.y + a.z*b.z + a.w*b.w;
}
__device__ __forceinline__ float wred(float v) {
    #pragma unroll
    for (int o = 32; o; o >>= 1) v += __shfl_down(v, o, 64);
    return v;
}
__device__ __forceinline__ float wred_all(float v) {
    #pragma unroll
    for (int o = 32; o; o >>= 1) v += __shfl_xor(v, o, 64);
    return v;
}
__device__ __forceinline__ float wmax_all(float v) {
    #pragma unroll
    for (int o = 32; o; o >>= 1) v = fmaxf(v, __shfl_xor(v, o, 64));
    return v;
}

// 4 rows per wave, CH float4-chunks per lane per row; vector held in registers.
// All 4*CH loads are issued before any use -> 4*CH KB in flight per wave.
template<int CH>
__device__ __forceinline__ void rows4_dot(const float* __restrict__ W, int ld,
                                          int row0, int rowmax,
                                          const float4 vec[CH], int lane, float s[4]) {
    float4 w[4][CH];
    #pragma unroll
    for (int r = 0; r < 4; ++r) {
        int row = row0 + r; if (row > rowmax) row = rowmax;
        const float4* Wr = (const float4*)(W + (size_t)row * ld);
        #pragma unroll
        for (int k = 0; k < CH; ++k) w[r][k] = Wr[lane + 64 * k];
    }
    #pragma unroll
    for (int r = 0; r < 4; ++r) {
        float acc = 0.f;
        #pragma unroll
        for (int k = 0; k < CH; ++k) acc += dot4(w[r][k], vec[k]);
        s[r] = acc;
    }
}

// K1: zero scratch accumulators, copy emb into comb, q = W_ma_attn @ emb + b  (1024 rows)
__global__ void k_init_q(const float* __restrict__ emb, const float* __restrict__ W,
                         const float* __restrict__ bias, float* __restrict__ ws) {
    int tid = threadIdx.x, bid = blockIdx.x;
    int gid = bid * 256 + tid;
    if (gid < 3072) ws[OFF_COMB + 512 + gid] = 0.f;   // c_enc/c_name/c_type accumulators
    if (gid == 3072) ws[OFF_SUMEXP] = 0.f;
    if (gid < 512) ws[OFF_COMB + gid] = emb[gid];
    int wave = tid >> 6, lane = tid & 63;
    const float4* e4 = (const float4*)emb;
    float4 ev[2] = { e4[lane], e4[lane + 64] };
    int row0 = (bid * 4 + wave) * 4;                   // < 1024
    float s[4];
    rows4_dot<2>(W, EE, row0, 1023, ev, lane, s);
    #pragma unroll
    for (int r = 0; r < 4; ++r) {
        float v = wred(s[r]);
        if (lane == 0) ws[OFF_Q + row0 + r] = v + bias[row0 + r];
    }
}

// K2: attention scores (enc 512, name 1024, type 1024 rows) + sim (block 160)
__global__ void k_scores(const float* __restrict__ enc, const float* __restrict__ name,
                         const float* __restrict__ type, float* __restrict__ ws) {
    int b = blockIdx.x, tid = threadIdx.x;
    int wave = tid >> 6, lane = tid & 63;
    if (b < 160) {
        const float* src; float* dst; int r0;
        if (b < 32)      { src = enc;  dst = ws + OFF_SENC;  r0 = b * 16 + wave * 4; }
        else if (b < 96) { src = name; dst = ws + OFF_SNAME; r0 = (b - 32) * 16 + wave * 4; }
        else             { src = type; dst = ws + OFF_STYPE; r0 = (b - 96) * 16 + wave * 4; }
        const float4* q4 = (const float4*)(ws + OFF_Q);
        float4 qv[4] = { q4[lane], q4[lane + 64], q4[lane + 128], q4[lane + 192] };
        float s[4];
        rows4_dot<4>(src, HH, r0, 1 << 30, qv, lane, s);  // rows always in range
        #pragma unroll
        for (int r = 0; r < 4; ++r) {
            float v = wred(s[r]);
            if (lane == 0) dst[r0 + r] = v;
        }
    } else {
        // sim = softmax(enc_last @ name_hiddens[:, -1, :].T)
        __shared__ float sd[8];
        const float4* el = (const float4*)(enc + (size_t)(TT - 1) * HH);
        for (int s8 = wave; s8 < 8; s8 += 4) {
            const float4* R = (const float4*)(name + ((size_t)s8 * TSS + (TSS - 1)) * HH);
            float s = 0.f;
            #pragma unroll
            for (int k = 0; k < 4; ++k) s += dot4(R[lane + 64 * k], el[lane + 64 * k]);
            s = wred(s);
            if (lane == 0) sd[s8] = s;
        }
        __syncthreads();
        if (tid == 0) {
            float m = -1e30f;
            for (int i = 0; i < 8; ++i) m = fmaxf(m, sd[i]);
            float e[8], su = 0.f;
            for (int i = 0; i < 8; ++i) { e[i] = expf(sd[i] - m); su += e[i]; }
            for (int i = 0; i < 8; ++i) ws[OFF_SIM + i] = e[i] / su;
        }
    }
}

// K3: context vectors with fused (redundant per-block) softmax over raw scores.
// 320 blocks: each handles 32 rows x 256 cols of one segment, atomic-acc into comb.
__global__ void k_ctx(const float* __restrict__ enc, const float* __restrict__ name,
                      const float* __restrict__ type, float* __restrict__ ws) {
    int b = blockIdx.x, tid = threadIdx.x;
    const float* src; const float* sc; float* dst; int i, n;
    if (b < 64)       { i = b;       src = enc;  sc = ws + OFF_SENC;  dst = ws + OFF_COMB + 512;  n = 512;  }
    else if (b < 192) { i = b - 64;  src = name; sc = ws + OFF_SNAME; dst = ws + OFF_COMB + 1536; n = 1024; }
    else              { i = b - 192; src = type; sc = ws + OFF_STYPE; dst = ws + OFF_COMB + 2560; n = 1024; }
    __shared__ float red[4];
    __shared__ float sh_m, sh_s;
    float mloc = -1e30f;
    for (int k = tid; k < n; k += 256) mloc = fmaxf(mloc, sc[k]);
    mloc = wmax_all(mloc);
    if ((tid & 63) == 0) red[tid >> 6] = mloc;
    __syncthreads();
    if (tid == 0) sh_m = fmaxf(fmaxf(red[0], red[1]), fmaxf(red[2], red[3]));
    __syncthreads();
    float m = sh_m;
    float sloc = 0.f;
    for (int k = tid; k < n; k += 256) sloc += expf(sc[k] - m);
    sloc = wred_all(sloc);
    __syncthreads();
    if ((tid & 63) == 0) red[tid >> 6] = sloc;
    __syncthreads();
    if (tid == 0) sh_s = red[0] + red[1] + red[2] + red[3];
    __syncthreads();
    float inv = 1.f / sh_s;
    int cc = i & 3;
    int r0 = (i >> 2) * 32;
    int col = cc * 256 + tid;
    float acc = 0.f;
    #pragma unroll 8
    for (int r = r0; r < r0 + 32; ++r) acc += expf(sc[r] - m) * src[(size_t)r * HH + col];
    atomicAdd(&dst[col], acc * inv);
}

// K4: x = tanh(W_ma_comb @ comb + b)   (512 rows x 3584)
__global__ void k_x(const float* __restrict__ W, const float* __restrict__ bias,
                    float* __restrict__ ws) {
    int tid = threadIdx.x, wave = tid >> 6, lane = tid & 63;
    int row = blockIdx.x * 4 + wave;                   // < 512
    const float4* Wr = (const float4*)(W + (size_t)row * 3584);
    const float4* c4 = (const float4*)(ws + OFF_COMB);
    float s = 0.f;
    #pragma unroll
    for (int k = 0; k < 14; ++k) s += dot4(Wr[lane + 64 * k], c4[lane + 64 * k]);
    s = wred(s);
    if (lane == 0) ws[OFF_X + row] = tanhf(s + bias[row]);
}

// K5: gates = W_ih @ x + W_hh @ h0 + b_ih + b_hh   (4096 rows)
__global__ void k_gates(const float* __restrict__ Wih, const float* __restrict__ Whh,
                        const float* __restrict__ bih, const float* __restrict__ bhh,
                        const float* __restrict__ h0, float* __restrict__ ws) {
    int tid = threadIdx.x, wave = tid >> 6, lane = tid & 63;
    int row0 = (blockIdx.x * 4 + wave) * 4;            // < 4096
    const float4* x4 = (const float4*)(ws + OFF_X);
    float4 xv[2] = { x4[lane], x4[lane + 64] };
    const float4* h4 = (const float4*)h0;
    float4 hv[4] = { h4[lane], h4[lane + 64], h4[lane + 128], h4[lane + 192] };
    float s1[4], s2[4];
    rows4_dot<2>(Wih, EE, row0, 4095, xv, lane, s1);
    rows4_dot<4>(Whh, HH, row0, 4095, hv, lane, s2);
    #pragma unroll
    for (int r = 0; r < 4; ++r) {
        float v = wred(s1[r] + s2[r]);
        int row = row0 + r;
        if (lane == 0) ws[OFF_GATES + row] = v + bih[row] + bhh[row];
    }
}

// K6: LSTM cell -> h1,c1 (to ws and d_out); then gen_p
__global__ void k_lstm(const float* __restrict__ c0, const float* __restrict__ nameh,
                       const float* __restrict__ typeh, const float* __restrict__ Wg,
                       const float* __restrict__ bg, float* __restrict__ ws,
                       float* __restrict__ out) {
    int t = threadIdx.x;                               // 1024 threads
    float ig = ws[OFF_GATES + t], fg = ws[OFF_GATES + 1024 + t];
    float gg = ws[OFF_GATES + 2048 + t], og = ws[OFF_GATES + 3072 + t];
    ig = 1.f / (1.f + expf(-ig));
    fg = 1.f / (1.f + expf(-fg));
    og = 1.f / (1.f + expf(-og));
    float c1 = fg * c0[t] + ig * tanhf(gg);
    float h1 = og * tanhf(c1);
    ws[OFF_C1 + t] = c1; ws[OFF_H1 + t] = h1;
    out[VV + MOOV + t] = h1;
    out[VV + MOOV + 1024 + t] = c1;
    __syncthreads();
    float p = Wg[t] * h1 + Wg[1024 + t] * nameh[t] + Wg[2048 + t] * typeh[t];
    if (t < 512) p += Wg[3072 + t] * ws[OFF_X + t];
    __shared__ float red[16];
    float su = p;
    #pragma unroll
    for (int o = 32; o; o >>= 1) su += __shfl_xor(su, o, 64);
    if ((t & 63) == 0) red[t >> 6] = su;
    __syncthreads();
    if (t == 0) {
        float ss = 0.f;
        for (int i = 0; i < 16; ++i) ss += red[i];
        ws[OFF_GENP] = 1.f / (1.f + expf(-(ss + bg[0])));
    }
}

// K7: big matvec exp(W_out @ h1 + b_out); h1 staged via LDS; 16 rows/block
__global__ void k_big(const float* __restrict__ W, const float* __restrict__ bias,
                      float* __restrict__ ws) {
    __shared__ float4 sh[256];
    __shared__ float part[4];
    int tid = threadIdx.x, wave = tid >> 6, lane = tid & 63;
    sh[tid] = ((const float4*)(ws + OFF_H1))[tid];
    __syncthreads();
    float4 hv[4] = { sh[lane], sh[lane + 64], sh[lane + 128], sh[lane + 192] };
    int row0 = (blockIdx.x * 4 + wave) * 4;
    float s[4];
    rows4_dot<4>(W, HH, row0, VV - 1, hv, lane, s);
    float partial = 0.f;
    #pragma unroll
    for (int r = 0; r < 4; ++r) {
        float v = wred(s[r]);
        int row = row0 + r;
        if (lane == 0 && row < VV) {
            float e = expf(v + bias[row]);
            ws[OFF_LOGIT + row] = e;
            partial += e;
        }
    }
    if (lane == 0) part[wave] = partial;
    __syncthreads();
    if (tid == 0) atomicAdd(&ws[OFF_SUMEXP], part[0] + part[1] + part[2] + part[3]);
}

// K8: qc = W_copy @ h1 + b_copy  (1024 rows)
__global__ void k_qc(const float* __restrict__ W, const float* __restrict__ bias,
                     float* __restrict__ ws) {
    int tid = threadIdx.x, wave = tid >> 6, lane = tid & 63;
    int row0 = (blockIdx.x * 4 + wave) * 4;            // < 1024
    const float4* h4 = (const float4*)(ws + OFF_H1);
    float4 hv[4] = { h4[lane], h4[lane + 64], h4[lane + 128], h4[lane + 192] };
    float s[4];
    rows4_dot<4>(W, HH, row0, 1023, hv, lane, s);
    #pragma unroll
    for (int r = 0; r < 4; ++r) {
        float v = wred(s[r]);
        if (lane == 0) ws[OFF_QC + row0 + r] = v + bias[row0 + r];
    }
}

// K9: attn scores[s,t] = type_hiddens[s,t,:] . qc  (1024 rows)
__global__ void k_attn(const float* __restrict__ type, float* __restrict__ ws) {
    int tid = threadIdx.x, wave = tid >> 6, lane = tid & 63;
    int row0 = (blockIdx.x * 4 + wave) * 4;            // < 1024
    const float4* q4 = (const float4*)(ws + OFF_QC);
    float4 qv[4] = { q4[lane], q4[lane + 64], q4[lane + 128], q4[lane + 192] };
    float s[4];
    rows4_dot<4>(type, HH, row0, 1023, qv, lane, s);
    #pragma unroll
    for (int r = 0; r < 4; ++r) {
        float v = wred(s[r]);
        if (lane == 0) ws[OFF_ATTN + row0 + r] = v;
    }
}

// K10: out[v] = gen_p * p_vocab[v]
__global__ void k_final1(const float* __restrict__ ws, float* __restrict__ out) {
    int g = blockIdx.x * 256 + threadIdx.x;
    if (g >= VV + MOOV) return;
    float gp = ws[OFF_GENP];
    float pv = (g < VV) ? ws[OFF_LOGIT + g] / ws[OFF_SUMEXP] : 0.f;
    out[g] = gp * pv;
}

// K11: per-s softmax over attn scores, scatter (1-gen_p)*sim[s]*attn_p into out
__global__ void k_scatter(const int* __restrict__ idx, const float* __restrict__ ws,
                          float* __restrict__ out) {
    int tid = threadIdx.x, s = tid >> 6, lane = tid & 63;   // 512 threads = 8 waves
    float sc0 = ws[OFF_ATTN + s * TSS + lane];
    float sc1 = ws[OFF_ATTN + s * TSS + 64 + lane];
    float m = wmax_all(fmaxf(sc0, sc1));
    float e0 = expf(sc0 - m), e1 = expf(sc1 - m);
    float su = wred_all(e0 + e1);
    float scale = (1.f - ws[OFF_GENP]) * ws[OFF_SIM + s] / su;
    atomicAdd(&out[idx[s * TSS + lane]],      scale * e0);
    atomicAdd(&out[idx[s * TSS + 64 + lane]], scale * e1);
}

// K12: log(clip(prob))
__global__ void k_final2(float* __restrict__ out) {
    int g = blockIdx.x * 256 + threadIdx.x;
    if (g >= VV + MOOV) return;
    out[g] = logf(fmaxf(out[g], 1e-10f));
}

extern "C" void kernel_launch(void* const* d_in, const int* in_sizes, int n_in,
                              void* d_out, int out_size, void* d_ws, size_t ws_size,
                              hipStream_t stream) {
    (void)in_sizes; (void)n_in; (void)out_size; (void)ws_size;
    const float* emb   = (const float*)d_in[0];
    const float* h0    = (const float*)d_in[1];
    const float* c0    = (const float*)d_in[2];
    const float* enc   = (const float*)d_in[3];
    const float* name  = (const float*)d_in[4];
    const float* type  = (const float*)d_in[5];
    const float* nameh = (const float*)d_in[6];
    const float* typeh = (const float*)d_in[7];
    const float* Wma   = (const float*)d_in[8];
    const float* bma   = (const float*)d_in[9];
    const float* Wmc   = (const float*)d_in[10];
    const float* bmc   = (const float*)d_in[11];
    const float* Wih   = (const float*)d_in[12];
    const float* Whh   = (const float*)d_in[13];
    const float* bih   = (const float*)d_in[14];
    const float* bhh   = (const float*)d_in[15];
    const float* Wcp   = (const float*)d_in[16];
    const float* bcp   = (const float*)d_in[17];
    const float* Wg    = (const float*)d_in[18];
    const float* bg    = (const float*)d_in[19];
    const float* Wout  = (const float*)d_in[20];
    const float* bout  = (const float*)d_in[21];
    const int*   tidx  = (const int*)d_in[22];
    float* out = (float*)d_out;
    float* ws  = (float*)d_ws;

    k_init_q  <<<64,    256, 0, stream>>>(emb, Wma, bma, ws);
    k_scores  <<<161,   256, 0, stream>>>(enc, name, type, ws);
    k_ctx     <<<320,   256, 0, stream>>>(enc, name, type, ws);
    k_x       <<<128,   256, 0, stream>>>(Wmc, bmc, ws);
    k_gates   <<<256,   256, 0, stream>>>(Wih, Whh, bih, bhh, h0, ws);
    k_lstm    <<<1,    1024, 0, stream>>>(c0, nameh, typeh, Wg, bg, ws, out);
    k_big     <<<3142,  256, 0, stream>>>(Wout, bout, ws);
    k_qc      <<<64,    256, 0, stream>>>(Wcp, bcp, ws);
    k_attn    <<<64,    256, 0, stream>>>(type, ws);
    k_final1  <<<197,   256, 0, stream>>>(ws, out);
    k_scatter <<<1,     512, 0, stream>>>(tidx, ws, out);
    k_final2  <<<197,   256, 0, stream>>>(out);
}